// Round 1
// baseline (443.993 us; speedup 1.0000x reference)
//
#include <hip/hip_runtime.h>

#define TWO_PI_F 6.283185f  // matches the reference's truncated constant

// One thread per row. Weights staged in LDS (wave-uniform broadcast reads,
// conflict-free). All inner loops fully unrolled -> feats/h/g live in VGPRs.
__global__ __launch_bounds__(256) void pixenc_f32(
    const float* __restrict__ x,
    const float* __restrict__ Bl,
    const float* __restrict__ W1, const float* __restrict__ b1,
    const float* __restrict__ W2, const float* __restrict__ b2,
    const float* __restrict__ W3, const float* __restrict__ b3,
    const float* __restrict__ W4, const float* __restrict__ b4,
    const float* __restrict__ W5, const float* __restrict__ b5,
    float* __restrict__ out, int N)
{
    __shared__ float sBl[32];
    __shared__ float sW1[656];
    __shared__ float sW2[256];
    __shared__ float sW3[256];
    __shared__ float sW4[256];
    __shared__ float sb1[16], sb2[16], sb3[16], sb4[16], sW5[16];
    __shared__ float sb5;

    const int t = threadIdx.x;
    for (int i = t; i < 656; i += 256) sW1[i] = W1[i];
    if (t < 256) { sW2[t] = W2[t]; sW3[t] = W3[t]; sW4[t] = W4[t]; }
    if (t < 32)  sBl[t] = Bl[t];
    if (t >= 32 && t < 48)  sb1[t - 32] = b1[t - 32];
    if (t >= 48 && t < 64)  sb2[t - 48] = b2[t - 48];
    if (t >= 64 && t < 80)  sb3[t - 64] = b3[t - 64];
    if (t >= 80 && t < 96)  sb4[t - 80] = b4[t - 80];
    if (t >= 96 && t < 112) sW5[t - 96] = W5[t - 96];
    if (t == 112) sb5 = b5[0];
    __syncthreads();

    const int i = blockIdx.x * 256 + t;
    if (i >= N) return;

    const float* xr = x + (long long)i * 11;

    // ---- features: [x[0:9], cos(2pi * xl@B), sin(2pi * xl@B)] -> 41 ----
    float feats[41];
    #pragma unroll
    for (int k = 0; k < 9; ++k) feats[k] = xr[k];
    const float xl0 = xr[9], xl1 = xr[10];
    #pragma unroll
    for (int f = 0; f < 16; ++f) {
        const float ang = TWO_PI_F * fmaf(xl0, sBl[f], xl1 * sBl[16 + f]);
        float s, c;
        __sincosf(ang, &s, &c);
        feats[9 + f]  = c;
        feats[25 + f] = s;
    }

    // ---- layer 1: 41 -> 16, ELU ----
    float h[16], g[16];
    #pragma unroll
    for (int j = 0; j < 16; ++j) h[j] = sb1[j];
    #pragma unroll
    for (int k = 0; k < 41; ++k) {
        const float f = feats[k];
        #pragma unroll
        for (int j = 0; j < 16; ++j) h[j] = fmaf(f, sW1[k * 16 + j], h[j]);
    }
    #pragma unroll
    for (int j = 0; j < 16; ++j) h[j] = h[j] > 0.f ? h[j] : __expf(h[j]) - 1.f;

    // ---- layer 2: 16 -> 16, ELU ----
    #pragma unroll
    for (int j = 0; j < 16; ++j) g[j] = sb2[j];
    #pragma unroll
    for (int k = 0; k < 16; ++k) {
        const float f = h[k];
        #pragma unroll
        for (int j = 0; j < 16; ++j) g[j] = fmaf(f, sW2[k * 16 + j], g[j]);
    }
    #pragma unroll
    for (int j = 0; j < 16; ++j) g[j] = g[j] > 0.f ? g[j] : __expf(g[j]) - 1.f;

    // ---- layer 3: 16 -> 16, ELU ----
    #pragma unroll
    for (int j = 0; j < 16; ++j) h[j] = sb3[j];
    #pragma unroll
    for (int k = 0; k < 16; ++k) {
        const float f = g[k];
        #pragma unroll
        for (int j = 0; j < 16; ++j) h[j] = fmaf(f, sW3[k * 16 + j], h[j]);
    }
    #pragma unroll
    for (int j = 0; j < 16; ++j) h[j] = h[j] > 0.f ? h[j] : __expf(h[j]) - 1.f;

    // ---- layer 4: 16 -> 16, ELU ----
    #pragma unroll
    for (int j = 0; j < 16; ++j) g[j] = sb4[j];
    #pragma unroll
    for (int k = 0; k < 16; ++k) {
        const float f = h[k];
        #pragma unroll
        for (int j = 0; j < 16; ++j) g[j] = fmaf(f, sW4[k * 16 + j], g[j]);
    }
    #pragma unroll
    for (int j = 0; j < 16; ++j) g[j] = g[j] > 0.f ? g[j] : __expf(g[j]) - 1.f;

    // ---- head: 16 -> 1 ----
    float o = sb5;
    #pragma unroll
    for (int j = 0; j < 16; ++j) o = fmaf(g[j], sW5[j], o);

    out[i] = o;
}

extern "C" void kernel_launch(void* const* d_in, const int* in_sizes, int n_in,
                              void* d_out, int out_size, void* d_ws, size_t ws_size,
                              hipStream_t stream) {
    const float* x  = (const float*)d_in[0];
    const float* Bl = (const float*)d_in[1];
    const float* W1 = (const float*)d_in[2];
    const float* b1 = (const float*)d_in[3];
    const float* W2 = (const float*)d_in[4];
    const float* b2 = (const float*)d_in[5];
    const float* W3 = (const float*)d_in[6];
    const float* b3 = (const float*)d_in[7];
    const float* W4 = (const float*)d_in[8];
    const float* b4 = (const float*)d_in[9];
    const float* W5 = (const float*)d_in[10];
    const float* b5 = (const float*)d_in[11];
    float* out = (float*)d_out;

    const int N = out_size;  // one output per row
    const int blocks = (N + 255) / 256;
    pixenc_f32<<<blocks, 256, 0, stream>>>(x, Bl, W1, b1, W2, b2, W3, b3,
                                           W4, b4, W5, b5, out, N);
}

// Round 2
// 178.397 us; speedup vs baseline: 2.4888x; 2.4888x over previous
//
#include <hip/hip_runtime.h>

typedef _Float16 half4_t __attribute__((ext_vector_type(4)));
typedef _Float16 half8_t __attribute__((ext_vector_type(8)));
typedef float    f32x4   __attribute__((ext_vector_type(4)));

__device__ __forceinline__ float elu(float v) {
    return v > 0.f ? v : __expf(v) - 1.f;
}

// Block = 256 threads = 4 waves; each wave owns 64 samples, processed as
// 4 MFMA sub-batches of 16. All layers computed as H^T = W^T * prev^T so
// each MFMA's D-layout feeds the next MFMA's B-operand directly (no shuffles).
__global__ __launch_bounds__(256) void pixenc_mfma(
    const float* __restrict__ x,
    const float* __restrict__ Bl,
    const float* __restrict__ W1, const float* __restrict__ b1,
    const float* __restrict__ W2, const float* __restrict__ b2,
    const float* __restrict__ W3, const float* __restrict__ b3,
    const float* __restrict__ W4, const float* __restrict__ b4,
    const float* __restrict__ W5, const float* __restrict__ b5,
    float* __restrict__ out, int N)
{
    // 56-half row stride: 112 B = 7*16 B -> b128 rows 16B-aligned, and both the
    // half8 writes and half4 B-fragment reads run at full LDS bandwidth.
    __shared__ _Float16 sF[256][56];

    const int t    = threadIdx.x;
    const int lane = t & 63;
    const int w    = t >> 6;
    const int g    = lane >> 4;   // 0..3 : k-subgroup
    const int m    = lane & 15;   // 0..15: A-row (hidden idx) / B-col (sample)

    // ---- per-lane weight fragments (A = W^T), biases as MFMA C-in ----
    half4_t A1[3], A2, A3, A4;
    #pragma unroll
    for (int c = 0; c < 3; ++c) {
        #pragma unroll
        for (int e = 0; e < 4; ++e) {
            const int k = c * 16 + g * 4 + e;        // feature index
            A1[c][e] = (k < 41) ? (_Float16)W1[k * 16 + m] : (_Float16)0.f;
        }
    }
    #pragma unroll
    for (int e = 0; e < 4; ++e) {
        const int r = g * 4 + e;                     // input-hidden index
        A2[e] = (_Float16)W2[r * 16 + m];
        A3[e] = (_Float16)W3[r * 16 + m];
        A4[e] = (_Float16)W4[r * 16 + m];
    }
    f32x4 c1, c2, c3, c4;
    float w5v[4];
    #pragma unroll
    for (int e = 0; e < 4; ++e) {
        const int r = g * 4 + e;                     // output-hidden index
        c1[e] = b1[r]; c2[e] = b2[r]; c3[e] = b3[r]; c4[e] = b4[r];
        w5v[e] = W5[r];
    }
    const float b5v = b5[0];

    // ---- per-thread sample: load x row, build 48 fp16 features in regs ----
    const int samp = blockIdx.x * 256 + t;
    const int sidx = samp < N ? samp : N - 1;
    const float* xr = x + (size_t)sidx * 11;
    float xv[11];
    #pragma unroll
    for (int k = 0; k < 11; ++k) xv[k] = xr[k];

    float cs[16], sn[16];
    #pragma unroll
    for (int f = 0; f < 16; ++f) {
        // z in "revolutions"; ref multiplies by 6.283185 (==2*pi to 5e-8 rel)
        const float z  = fmaf(xv[9], Bl[f], xv[10] * Bl[16 + f]);
        const float zf = z - floorf(z);              // [0,1) for v_sin/v_cos
        cs[f] = __builtin_amdgcn_cosf(zf);
        sn[f] = __builtin_amdgcn_sinf(zf);
    }

    #pragma unroll
    for (int c = 0; c < 6; ++c) {
        half8_t v;
        #pragma unroll
        for (int e = 0; e < 8; ++e) {
            const int k = c * 8 + e;
            float fv;
            if (k < 9)       fv = xv[k];
            else if (k < 25) fv = cs[k - 9];
            else if (k < 41) fv = sn[k - 25];
            else             fv = 0.f;               // zero-pad 41..47
            v[e] = (_Float16)fv;
        }
        *(half8_t*)&sF[t][c * 8] = v;
    }
    __syncthreads();

    // ---- 4 sub-batches of 16 samples per wave ----
    #pragma unroll
    for (int s = 0; s < 4; ++s) {
        const _Float16* rowp = &sF[w * 64 + s * 16 + m][0];

        // layer 1: K=48 over 3 chained MFMAs, bias via C-in
        f32x4 acc = c1;
        #pragma unroll
        for (int c = 0; c < 3; ++c) {
            const half4_t bf = *(const half4_t*)&rowp[c * 16 + g * 4];
            acc = __builtin_amdgcn_mfma_f32_16x16x16f16(A1[c], bf, acc, 0, 0, 0);
        }

        half4_t h;
        #pragma unroll
        for (int e = 0; e < 4; ++e) h[e] = (_Float16)elu(acc[e]);
        acc = __builtin_amdgcn_mfma_f32_16x16x16f16(A2, h, c2, 0, 0, 0);
        #pragma unroll
        for (int e = 0; e < 4; ++e) h[e] = (_Float16)elu(acc[e]);
        acc = __builtin_amdgcn_mfma_f32_16x16x16f16(A3, h, c3, 0, 0, 0);
        #pragma unroll
        for (int e = 0; e < 4; ++e) h[e] = (_Float16)elu(acc[e]);
        acc = __builtin_amdgcn_mfma_f32_16x16x16f16(A4, h, c4, 0, 0, 0);

        // head: 16 -> 1, reduce the 4 k-subgroups across lanes
        float p = 0.f;
        #pragma unroll
        for (int e = 0; e < 4; ++e) p = fmaf(elu(acc[e]), w5v[e], p);
        p += __shfl_xor(p, 16, 64);
        p += __shfl_xor(p, 32, 64);

        const int o = blockIdx.x * 256 + w * 64 + s * 16 + m;
        if (g == 0 && o < N) out[o] = p + b5v;
    }
}

extern "C" void kernel_launch(void* const* d_in, const int* in_sizes, int n_in,
                              void* d_out, int out_size, void* d_ws, size_t ws_size,
                              hipStream_t stream) {
    const float* x  = (const float*)d_in[0];
    const float* Bl = (const float*)d_in[1];
    const float* W1 = (const float*)d_in[2];
    const float* b1 = (const float*)d_in[3];
    const float* W2 = (const float*)d_in[4];
    const float* b2 = (const float*)d_in[5];
    const float* W3 = (const float*)d_in[6];
    const float* b3 = (const float*)d_in[7];
    const float* W4 = (const float*)d_in[8];
    const float* b4 = (const float*)d_in[9];
    const float* W5 = (const float*)d_in[10];
    const float* b5 = (const float*)d_in[11];
    float* out = (float*)d_out;

    const int N = out_size;
    const int blocks = (N + 255) / 256;
    pixenc_mfma<<<blocks, 256, 0, stream>>>(x, Bl, W1, b1, W2, b2, W3, b3,
                                            W4, b4, W5, b5, out, N);
}

// Round 4
// 150.752 us; speedup vs baseline: 2.9452x; 1.1834x over previous
//
#include <hip/hip_runtime.h>

typedef __fp16   fp16x2  __attribute__((ext_vector_type(2)));
typedef _Float16 half4_t __attribute__((ext_vector_type(4)));
typedef float    f32x4   __attribute__((ext_vector_type(4)));

#define CH 4  // chunks of 256 samples per block

__device__ __forceinline__ unsigned pk(float a, float b) {
    fp16x2 h = __builtin_amdgcn_cvt_pkrtz(a, b);
    return __builtin_bit_cast(unsigned, h);
}
__device__ __forceinline__ float elu(float v) {
    return v > 0.f ? v : __expf(v) - 1.f;
}

// Feature layout in LDS (48 slots): [x0..x8 | pad*7 | cos0..15 | sin0..15].
// A1 rows are permuted identically, so the pad is free (41->48 was padded
// anyway). Per-wave-private LDS rows -> NO barriers in the whole kernel.
__global__ __launch_bounds__(256, 4) void pixenc_mfma2(
    const float* __restrict__ x,
    const float* __restrict__ Bl,
    const float* __restrict__ W1, const float* __restrict__ b1,
    const float* __restrict__ W2, const float* __restrict__ b2,
    const float* __restrict__ W3, const float* __restrict__ b3,
    const float* __restrict__ W4, const float* __restrict__ b4,
    const float* __restrict__ W5, const float* __restrict__ b5,
    float* __restrict__ out, int N)
{
    // 56-half (112 B) row stride: rows 16B-aligned, 2-way-max (free) bank
    // aliasing on both the b128 writes and the b64 B-fragment reads.
    __shared__ _Float16 sF[256][56];

    const int t    = threadIdx.x;
    const int lane = t & 63;
    const int w    = t >> 6;
    const int g    = lane >> 4;   // k-subgroup
    const int m    = lane & 15;   // hidden idx (A) / sample col (B)

    // ---- per-lane weight fragments (A = W^T), biases as MFMA C-in ----
    half4_t A1[3], A2, A3, A4;
    #pragma unroll
    for (int c = 0; c < 3; ++c) {
        #pragma unroll
        for (int e = 0; e < 4; ++e) {
            const int slot = c * 16 + g * 4 + e;
            const int r = slot < 9 ? slot : slot - 7;   // feature row in W1
            const bool valid = (slot < 9) | (slot >= 16);
            A1[c][e] = valid ? (_Float16)W1[r * 16 + m] : (_Float16)0.f;
        }
    }
    #pragma unroll
    for (int e = 0; e < 4; ++e) {
        const int r = g * 4 + e;
        A2[e] = (_Float16)W2[r * 16 + m];
        A3[e] = (_Float16)W3[r * 16 + m];
        A4[e] = (_Float16)W4[r * 16 + m];
    }
    f32x4 c1, c2, c3, c4;
    float w5v[4];
    #pragma unroll
    for (int e = 0; e < 4; ++e) {
        const int r = g * 4 + e;
        c1[e] = b1[r]; c2[e] = b2[r]; c3[e] = b3[r]; c4[e] = b4[r];
        w5v[e] = W5[r];
    }
    const float b5v = b5[0];

    const int base = blockIdx.x * (256 * CH);

    // prefetch chunk 0's x row
    float xv[11];
    {
        int s0 = base + t; if (s0 >= N) s0 = N - 1;
        const float* p = x + (size_t)s0 * 11;
        #pragma unroll
        for (int k = 0; k < 11; ++k) xv[k] = p[k];
    }

    #pragma unroll
    for (int c = 0; c < CH; ++c) {
        // ---- prefetch next chunk's x row (hides HBM latency under compute) ----
        float xn[11];
        if (c + 1 < CH) {
            int s1 = base + (c + 1) * 256 + t; if (s1 >= N) s1 = N - 1;
            const float* p = x + (size_t)s1 * 11;
            #pragma unroll
            for (int k = 0; k < 11; ++k) xn[k] = p[k];
        }

        // ---- Fourier features (v_fract + v_cos/v_sin on revolutions) ----
        float zf[16];
        #pragma unroll
        for (int f = 0; f < 16; ++f) {
            const float z = fmaf(xv[9], Bl[f], xv[10] * Bl[16 + f]);
            zf[f] = __builtin_amdgcn_fractf(z);
        }

        unsigned q[24];
        q[0] = pk(xv[0], xv[1]); q[1] = pk(xv[2], xv[3]);
        q[2] = pk(xv[4], xv[5]); q[3] = pk(xv[6], xv[7]);
        q[4] = pk(xv[8], 0.f);   q[5] = 0u; q[6] = 0u; q[7] = 0u;
        #pragma unroll
        for (int p2 = 0; p2 < 8; ++p2) {
            q[8  + p2] = pk(__builtin_amdgcn_cosf(zf[2 * p2]),
                            __builtin_amdgcn_cosf(zf[2 * p2 + 1]));
            q[16 + p2] = pk(__builtin_amdgcn_sinf(zf[2 * p2]),
                            __builtin_amdgcn_sinf(zf[2 * p2 + 1]));
        }

        // ---- write own row (per-wave region; intra-wave dep only) ----
        uint4* dst = (uint4*)&sF[t][0];
        #pragma unroll
        for (int j = 0; j < 6; ++j)
            dst[j] = make_uint4(q[4 * j], q[4 * j + 1], q[4 * j + 2], q[4 * j + 3]);

        // ---- 4 MFMA sub-batches of 16 samples ----
        #pragma unroll
        for (int s = 0; s < 4; ++s) {
            const _Float16* rowp = &sF[w * 64 + s * 16 + m][0];

            f32x4 acc = c1;
            #pragma unroll
            for (int cc = 0; cc < 3; ++cc) {
                const half4_t bf = *(const half4_t*)&rowp[cc * 16 + g * 4];
                acc = __builtin_amdgcn_mfma_f32_16x16x16f16(A1[cc], bf, acc, 0, 0, 0);
            }

            half4_t h;
            #pragma unroll
            for (int e = 0; e < 4; ++e) h[e] = (_Float16)elu(acc[e]);
            acc = __builtin_amdgcn_mfma_f32_16x16x16f16(A2, h, c2, 0, 0, 0);
            #pragma unroll
            for (int e = 0; e < 4; ++e) h[e] = (_Float16)elu(acc[e]);
            acc = __builtin_amdgcn_mfma_f32_16x16x16f16(A3, h, c3, 0, 0, 0);
            #pragma unroll
            for (int e = 0; e < 4; ++e) h[e] = (_Float16)elu(acc[e]);
            acc = __builtin_amdgcn_mfma_f32_16x16x16f16(A4, h, c4, 0, 0, 0);

            float p = 0.f;
            #pragma unroll
            for (int e = 0; e < 4; ++e) p = fmaf(elu(acc[e]), w5v[e], p);
            p += __shfl_xor(p, 16, 64);
            p += __shfl_xor(p, 32, 64);

            const int o = base + c * 256 + w * 64 + s * 16 + m;
            if (g == 0 && o < N) out[o] = p + b5v;
        }

        #pragma unroll
        for (int k = 0; k < 11; ++k) xv[k] = xn[k];
    }
}

extern "C" void kernel_launch(void* const* d_in, const int* in_sizes, int n_in,
                              void* d_out, int out_size, void* d_ws, size_t ws_size,
                              hipStream_t stream) {
    const float* x  = (const float*)d_in[0];
    const float* Bl = (const float*)d_in[1];
    const float* W1 = (const float*)d_in[2];
    const float* b1 = (const float*)d_in[3];
    const float* W2 = (const float*)d_in[4];
    const float* b2 = (const float*)d_in[5];
    const float* W3 = (const float*)d_in[6];
    const float* b3 = (const float*)d_in[7];
    const float* W4 = (const float*)d_in[8];
    const float* b4 = (const float*)d_in[9];
    const float* W5 = (const float*)d_in[10];
    const float* b5 = (const float*)d_in[11];
    float* out = (float*)d_out;

    const int N = out_size;
    const int blocks = (N + 256 * CH - 1) / (256 * CH);
    pixenc_mfma2<<<blocks, 256, 0, stream>>>(x, Bl, W1, b1, W2, b2, W3, b3,
                                             W4, b4, W5, b5, out, N);
}